// Round 7
// baseline (4404.324 us; speedup 1.0000x reference)
//
#include <hip/hip_runtime.h>
#include <math.h>

#define BB 128
#define NN 256
#define HH 512
#define T_STEPS 32
#define NBLK 256

__device__ __forceinline__ float fast_tanh(float x) {
    float e = __expf(2.0f * x);
    return 1.0f - 2.0f / (1.0f + e);
}
__device__ __forceinline__ float fast_sigmoid(float x) {
    return 1.0f / (1.0f + __expf(-x));
}

// ---------------- W1e = enc @ W1^T (32768x512x512 fp32, LDS-tiled, swizzled)
#define SW(j, i) ((i) ^ ((((j) >> 2) & 7) << 2))
__global__ __launch_bounds__(256) void w1e_gemm(const float* __restrict__ enc,
                                                const float* __restrict__ W1,
                                                float* __restrict__ W1e) {
    __shared__ float As[32][64];
    __shared__ float Bs[32][64];
    int tid = threadIdx.x;
    int i0 = blockIdx.x * 64;
    int k0 = blockIdx.y * 64;
    int tx = tid & 15, ty = tid >> 4;
    int srow = tid >> 3, sq = tid & 7;

    float acc[4][4];
#pragma unroll
    for (int a = 0; a < 4; a++)
#pragma unroll
        for (int c = 0; c < 4; c++) acc[a][c] = 0.f;

    for (int j0 = 0; j0 < HH; j0 += 32) {
#pragma unroll
        for (int p = 0; p < 2; p++) {
            int row = p * 32 + srow;
            float4 av = *(const float4*)(enc + (size_t)(i0 + row) * HH + j0 + sq * 4);
            float4 bv = *(const float4*)(W1 + (size_t)(k0 + row) * HH + j0 + sq * 4);
#pragma unroll
            for (int c = 0; c < 4; c++) {
                int j = sq * 4 + c;
                float va = (c == 0) ? av.x : (c == 1) ? av.y : (c == 2) ? av.z : av.w;
                float vb = (c == 0) ? bv.x : (c == 1) ? bv.y : (c == 2) ? bv.z : bv.w;
                As[j][SW(j, row)] = va;
                Bs[j][SW(j, row)] = vb;
            }
        }
        __syncthreads();
#pragma unroll
        for (int j = 0; j < 32; j++) {
            float4 a = *(const float4*)&As[j][SW(j, tx * 4)];
            float4 b = *(const float4*)&Bs[j][SW(j, ty * 4)];
            float ar[4] = {a.x, a.y, a.z, a.w};
            float br[4] = {b.x, b.y, b.z, b.w};
#pragma unroll
            for (int ai = 0; ai < 4; ai++)
#pragma unroll
                for (int bk = 0; bk < 4; bk++)
                    acc[ai][bk] += ar[ai] * br[bk];
        }
        __syncthreads();
    }
#pragma unroll
    for (int ai = 0; ai < 4; ai++) {
        float4 r = make_float4(acc[ai][0], acc[ai][1], acc[ai][2], acc[ai][3]);
        *(float4*)(W1e + (size_t)(i0 + tx * 4 + ai) * HH + k0 + ty * 4) = r;
    }
}

__global__ void init_kernel(float* __restrict__ hB0, int* __restrict__ bar) {
    int tid = blockIdx.x * blockDim.x + threadIdx.x;
    int nt = gridDim.x * blockDim.x;
    for (int i = tid; i < HH * BB; i += nt) hB0[i] = 0.f;
    for (int i = tid; i < 256; i += nt) bar[i] = 0;
}

// device-scope barrier, one fresh slot per use (slots zeroed by init_kernel)
__device__ __forceinline__ void gbar(int* cnt, int* flag, int slot) {
    __syncthreads();
    if (threadIdx.x == 0) {
        __threadfence();
        int prev = __hip_atomic_fetch_add(&cnt[slot], 1, __ATOMIC_ACQ_REL,
                                          __HIP_MEMORY_SCOPE_AGENT);
        if (prev == NBLK - 1) {
            __hip_atomic_store(&flag[slot], 1, __ATOMIC_RELEASE,
                               __HIP_MEMORY_SCOPE_AGENT);
        } else {
            while (__hip_atomic_load(&flag[slot], __ATOMIC_ACQUIRE,
                                     __HIP_MEMORY_SCOPE_AGENT) == 0)
                __builtin_amdgcn_s_sleep(1);
        }
        __threadfence();
    }
    __syncthreads();
}

// combine two half-row softmax stats -> (idx, logp, entropy)
__device__ __forceinline__ void combine_stats(const float* __restrict__ stats,
                                              int i, int& idx, float& lp, float& en) {
    const float* s0 = stats + ((size_t)i * 2 + 0) * 4;
    const float* s1 = stats + ((size_t)i * 2 + 1) * 4;
    float m0 = s0[0], S0 = s0[1], E0 = s0[2]; int i0 = (int)s0[3];
    float m1 = s1[0], S1 = s1[1], E1 = s1[2]; int i1 = (int)s1[3];
    float m;
    if (m1 > m0) { m = m1; idx = i1; } else { m = m0; idx = i0; }
    float c0 = expf(m0 - m), c1 = expf(m1 - m);
    float S = S0 * c0 + S1 * c1;
    float E = (E0 + (m0 - m) * S0) * c0 + (E1 + (m1 - m) * S1) * c1;
    float inv = 1.0f / S;
    lp = logf(inv + 1e-9f);
    en = logf(S) - inv * E;
}

// persistent k-partitioned decoder: 256 blocks x 1024 threads, 3 barriers/step
__global__ __launch_bounds__(1024) void decode_kernel(
    const float* __restrict__ enc,
    const float* __restrict__ w_ih, const float* __restrict__ w_hh,
    const float* __restrict__ b_ih, const float* __restrict__ b_hh,
    const float* __restrict__ W2, const float* __restrict__ v,
    const float* __restrict__ W1e,
    float* __restrict__ hB0, float* __restrict__ hB1,
    float* __restrict__ W2hg, float* __restrict__ stats,
    int* __restrict__ bcnt, int* __restrict__ bflag,
    float* __restrict__ out) {
    __shared__ float wl[12 * HH];    // 24KB: GRU weights for k0,k0+1  [s][m][g][j]
    __shared__ float wl2[2 * HH];    // 4KB: W2 rows k0,k0+1
    __shared__ float vl[HH];         // 2KB
    __shared__ float scr[6144];      // 24KB: A partials / B partials / C u_l
    __shared__ int idx_l[BB];
    __shared__ int mask_l[128];      // this block's n-half mask (row role)
    __shared__ float redv[12];
    __shared__ int redi[4];
    __shared__ float s_hm;

    int blk = blockIdx.x, tid = threadIdx.x;
    int k0 = blk * 2;

    for (int u = tid; u < 12 * HH; u += 1024) {
        int r = u >> 9, j = u & (HH - 1);
        int s = r / 6, rem = r % 6;
        int m = rem / 3, g = rem % 3;
        const float* src = m ? w_hh : w_ih;
        wl[u] = src[(size_t)(g * HH + k0 + s) * HH + j];
    }
    for (int u = tid; u < 2 * HH; u += 1024)
        wl2[u] = W2[(size_t)(k0 + (u >> 9)) * HH + (u & (HH - 1))];
    if (tid < HH) vl[tid] = v[tid];
    if (tid < 128) mask_l[tid] = 0;
    __syncthreads();

    int b = tid & 127, grp = tid >> 7, s = grp & 1, jq = grp >> 1;
    int sb = blk >> 1, hf = blk & 1;
    int wv = tid >> 6, lane = tid & 63;

    float vr[8];
#pragma unroll
    for (int c = 0; c < 8; c++) vr[c] = vl[lane * 8 + c];

    for (int t = 0; t < T_STEPS; t++) {
        const float* hcur = (t & 1) ? hB1 : hB0;
        float* hnext = (t & 1) ? hB0 : hB1;

        // ---- A: combine prev stats (+outputs t-1) + GRU ----
        if (t > 0) {
            if (tid < BB) {
                int idx; float lp, en;
                combine_stats(stats, tid, idx, lp, en);
                idx_l[tid] = idx;
                if (blk < BB && tid == blk) {
                    out[blk * T_STEPS + (t - 1)] = (float)idx;
                    out[BB * T_STEPS + blk * T_STEPS + (t - 1)] = lp;
                    out[2 * BB * T_STEPS + blk * T_STEPS + (t - 1)] = en;
                }
            }
            __syncthreads();
        }
        {
            float a0 = 0, a1 = 0, a2 = 0, a3 = 0, a4 = 0, a5 = 0;
            if (t > 0) {
                const float* xrow = enc + ((size_t)b * NN + idx_l[b]) * HH;
                const float* hrow = hcur + (size_t)b * HH;
                const float* wp = wl + s * 6 * HH;
                int j0 = jq * 128;
#pragma unroll 4
                for (int j = j0; j < j0 + 128; j += 4) {
                    float4 xv = *(const float4*)(xrow + j);
                    float4 hv = *(const float4*)(hrow + j);
                    float4 wi0 = *(const float4*)(wp + j);
                    float4 wi1 = *(const float4*)(wp + HH + j);
                    float4 wi2 = *(const float4*)(wp + 2 * HH + j);
                    float4 wh0 = *(const float4*)(wp + 3 * HH + j);
                    float4 wh1 = *(const float4*)(wp + 4 * HH + j);
                    float4 wh2 = *(const float4*)(wp + 5 * HH + j);
                    a0 += xv.x * wi0.x + xv.y * wi0.y + xv.z * wi0.z + xv.w * wi0.w;
                    a1 += xv.x * wi1.x + xv.y * wi1.y + xv.z * wi1.z + xv.w * wi1.w;
                    a2 += xv.x * wi2.x + xv.y * wi2.y + xv.z * wi2.z + xv.w * wi2.w;
                    a3 += hv.x * wh0.x + hv.y * wh0.y + hv.z * wh0.z + hv.w * wh0.w;
                    a4 += hv.x * wh1.x + hv.y * wh1.y + hv.z * wh1.z + hv.w * wh1.w;
                    a5 += hv.x * wh2.x + hv.y * wh2.y + hv.z * wh2.z + hv.w * wh2.w;
                }
            }
            float* p = scr + grp * 768 + b * 6;
            p[0] = a0; p[1] = a1; p[2] = a2; p[3] = a3; p[4] = a4; p[5] = a5;
        }
        __syncthreads();
        if (tid < 256) {
            int ss = tid >> 7, bb = tid & 127;
            int k = k0 + ss;
            float ir = 0, iz = 0, inn = 0, hr = 0, hz = 0, hn2 = 0;
#pragma unroll
            for (int g = 0; g < 4; g++) {
                const float* p = scr + ((g << 1) | ss) * 768 + bb * 6;
                ir += p[0]; iz += p[1]; inn += p[2];
                hr += p[3]; hz += p[4]; hn2 += p[5];
            }
            float r = fast_sigmoid(ir + b_ih[k] + hr + b_hh[k]);
            float z = fast_sigmoid(iz + b_ih[HH + k] + hz + b_hh[HH + k]);
            float n = fast_tanh(inn + b_ih[2 * HH + k] + r * (hn2 + b_hh[2 * HH + k]));
            float hold = hcur[(size_t)bb * HH + k];
            hnext[(size_t)bb * HH + k] = (1.f - z) * n + z * hold;
        }
        gbar(bcnt, bflag, t * 3 + 0);

        // ---- B: W2h (k-partitioned) ----
        {
            float acc = 0.f;
            const float* hrow = hnext + (size_t)b * HH;
            const float* wp = wl2 + s * HH;
            int j0 = jq * 128;
#pragma unroll 4
            for (int j = j0; j < j0 + 128; j += 4) {
                float4 hv = *(const float4*)(hrow + j);
                float4 w = *(const float4*)(wp + j);
                acc += hv.x * w.x + hv.y * w.y + hv.z * w.z + hv.w * w.w;
            }
            scr[grp * 128 + b] = acc;
        }
        __syncthreads();
        if (tid < 256) {
            int ss = tid >> 7, bb = tid & 127;
            float w2v = 0;
#pragma unroll
            for (int g = 0; g < 4; g++) w2v += scr[(((g << 1) | ss) * 128) + bb];
            W2hg[(size_t)bb * HH + k0 + ss] = w2v;
        }
        gbar(bcnt, bflag, t * 3 + 1);

        // ---- C: score (wave per n, lane-major k) + half-row stats ----
        {
            if (t > 0 && tid == 0) {
                int ix = idx_l[sb];
                if ((ix >> 7) == hf) mask_l[ix & 127] = 1;
            }
            float w2r[8];
            const float* w2row = W2hg + (size_t)sb * HH + lane * 8;
            float4 wa = *(const float4*)(w2row);
            float4 wb = *(const float4*)(w2row + 4);
            w2r[0] = wa.x; w2r[1] = wa.y; w2r[2] = wa.z; w2r[3] = wa.w;
            w2r[4] = wb.x; w2r[5] = wb.y; w2r[6] = wb.z; w2r[7] = wb.w;
            const float* Wbase = W1e + ((size_t)sb * NN + hf * 128) * HH;
#pragma unroll 2
            for (int nn = 0; nn < 8; nn++) {
                int nl = (wv << 3) + nn;
                const float* Wp = Wbase + (size_t)nl * HH + lane * 8;
                float4 A0 = *(const float4*)(Wp);
                float4 A1 = *(const float4*)(Wp + 4);
                float p = fast_tanh(A0.x + w2r[0]) * vr[0] +
                          fast_tanh(A0.y + w2r[1]) * vr[1] +
                          fast_tanh(A0.z + w2r[2]) * vr[2] +
                          fast_tanh(A0.w + w2r[3]) * vr[3] +
                          fast_tanh(A1.x + w2r[4]) * vr[4] +
                          fast_tanh(A1.y + w2r[5]) * vr[5] +
                          fast_tanh(A1.z + w2r[6]) * vr[6] +
                          fast_tanh(A1.w + w2r[7]) * vr[7];
                p += __shfl_xor(p, 1);
                p += __shfl_xor(p, 2);
                p += __shfl_xor(p, 4);
                p += __shfl_xor(p, 8);
                p += __shfl_xor(p, 16);
                p += __shfl_xor(p, 32);
                if (lane == 0) scr[2048 + nl] = p;
            }
        }
        __syncthreads();
        if (tid < 128) {
            float val = mask_l[tid] ? -1.0e9f : scr[2048 + tid];
            float bv = val; int bi = hf * 128 + tid;   // GLOBAL n index (fix)
            for (int off = 32; off > 0; off >>= 1) {
                float ov = __shfl_down(bv, off);
                int oi = __shfl_down(bi, off);
                if (ov > bv || (ov == bv && oi < bi)) { bv = ov; bi = oi; }
            }
            if ((tid & 63) == 0) { redv[tid >> 6] = bv; redi[tid >> 6] = bi; }
        }
        __syncthreads();
        if (tid == 0) {
            if (redv[1] > redv[0]) { s_hm = redv[1]; redi[2] = redi[1]; }
            else { s_hm = redv[0]; redi[2] = redi[0]; }
        }
        __syncthreads();
        if (tid < 128) {
            float val = mask_l[tid] ? -1.0e9f : scr[2048 + tid];
            float d = val - s_hm;
            float e = expf(d);
            float ed = e * d;
            for (int off = 32; off > 0; off >>= 1) {
                e += __shfl_down(e, off);
                ed += __shfl_down(ed, off);
            }
            if ((tid & 63) == 0) { redv[4 + (tid >> 6)] = e; redv[8 + (tid >> 6)] = ed; }
        }
        __syncthreads();
        if (tid == 0) {
            float* sp = stats + ((size_t)sb * 2 + hf) * 4;
            sp[0] = s_hm;
            sp[1] = redv[4] + redv[5];
            sp[2] = redv[8] + redv[9];
            sp[3] = (float)redi[2];
        }
        gbar(bcnt, bflag, t * 3 + 2);
    }

    // epilogue: outputs for t = T-1
    if (blk < BB && tid == 0) {
        int idx; float lp, en;
        combine_stats(stats, blk, idx, lp, en);
        out[blk * T_STEPS + (T_STEPS - 1)] = (float)idx;
        out[BB * T_STEPS + blk * T_STEPS + (T_STEPS - 1)] = lp;
        out[2 * BB * T_STEPS + blk * T_STEPS + (T_STEPS - 1)] = en;
    }
}

extern "C" void kernel_launch(void* const* d_in, const int* in_sizes, int n_in,
                              void* d_out, int out_size, void* d_ws, size_t ws_size,
                              hipStream_t stream) {
    const float* enc  = (const float*)d_in[0];
    const float* w_ih = (const float*)d_in[1];
    const float* w_hh = (const float*)d_in[2];
    const float* b_ih = (const float*)d_in[3];
    const float* b_hh = (const float*)d_in[4];
    const float* W1   = (const float*)d_in[5];
    const float* W2   = (const float*)d_in[6];
    const float* v    = (const float*)d_in[7];
    float* out = (float*)d_out;

    float* ws = (float*)d_ws;
    float* W1e   = ws;                               // 16777216 floats (64MB)
    float* hB0   = W1e + (size_t)BB * NN * HH;       // 65536
    float* hB1   = hB0 + (size_t)BB * HH;            // 65536
    float* W2hg  = hB1 + (size_t)BB * HH;            // 65536
    float* stats = W2hg + (size_t)BB * HH;           // 1024
    int*   bar   = (int*)(stats + 1024);             // 256 ints (cnt 128 + flag 128)
    int*   bcnt  = bar;
    int*   bflag = bar + 128;

    init_kernel<<<64, 256, 0, stream>>>(hB0, bar);
    w1e_gemm<<<dim3((BB * NN) / 64, HH / 64), 256, 0, stream>>>(enc, W1, W1e);

    void* args[] = {
        (void*)&enc, (void*)&w_ih, (void*)&w_hh, (void*)&b_ih, (void*)&b_hh,
        (void*)&W2, (void*)&v, (void*)&W1e, (void*)&hB0, (void*)&hB1,
        (void*)&W2hg, (void*)&stats, (void*)&bcnt, (void*)&bflag, (void*)&out};
    hipLaunchCooperativeKernel((void*)decode_kernel, dim3(NBLK), dim3(1024),
                               args, 0, stream);
}